// Round 12
// baseline (109.450 us; speedup 1.0000x reference)
//
#include <hip/hip_runtime.h>

#define Q 4096
#define L 8192
#define RW 4                    // ctx rows per wave
#define NCW (L / RW)            // 2048 ctx waves (= partial rows)
#define NCBLK (NCW / 4)         // 512 ctx blocks
#define RWK 2                   // KwL rows per wave
#define NKBLK ((Q / RWK) / 4)   // 512 KwL blocks

// ---------------------------------------------------------------------------
// Pass 1 — ZERO block barriers anywhere.
// Family A (blocks [0,NCBLK)): each wave autonomously does online softmax-
//   weighted sum over RW=4 full rows. Row dot via wave shfl_xor allreduce;
//   accumulate re-reads the row from L2 (just fetched, resident). acc[16]
//   float4 persistent; no row buffer, no LDS.
// Family B (blocks [NCBLK,NCBLK+NKBLK)): out1[i] = Kw[i,0:Q].q, wave-per-row.
// ---------------------------------------------------------------------------
__global__ __launch_bounds__(256) void pass1_kernel(
    const float* __restrict__ qvec, const float* __restrict__ ctx,
    const float* __restrict__ Kw, float* __restrict__ partial,
    float* __restrict__ m_arr, float* __restrict__ Z_arr,
    float* __restrict__ out1)
{
    const int tid  = threadIdx.x;
    const int lane = tid & 63;
    const int wid  = tid >> 6;
    const float4* __restrict__ qv = (const float4*)qvec;

    if (blockIdx.x < NCBLK) {
        const int gw = blockIdx.x * 4 + wid;             // 0..2047
        const float4* __restrict__ cb = (const float4*)ctx;

        float4 acc[16];
        #pragma unroll
        for (int k = 0; k < 16; ++k) acc[k] = make_float4(0.f, 0.f, 0.f, 0.f);
        float m = -3.4e38f, Z = 0.f;

        for (int r = 0; r < RW; ++r) {
            const size_t rowb = (size_t)(gw * RW + r) * (Q / 4);

            // ---- dot phase: stream row (HBM) + q (L1-hot) ----
            float d = 0.f;
            #pragma unroll 4
            for (int k = 0; k < 16; ++k) {
                float4 x = cb[rowb + k * 64 + lane];
                float4 y = qv[k * 64 + lane];
                d = fmaf(x.x, y.x, d); d = fmaf(x.y, y.y, d);
                d = fmaf(x.z, y.z, d); d = fmaf(x.w, y.w, d);
            }
            // wave allreduce — every lane gets the full-row score
            #pragma unroll
            for (int off = 1; off < 64; off <<= 1)
                d += __shfl_xor(d, off, 64);

            // ---- online update (wave-uniform) ----
            if (d > m) {
                const float sc = __expf(m - d);          // first row: 0
                Z *= sc;
                #pragma unroll
                for (int k = 0; k < 16; ++k) {
                    acc[k].x *= sc; acc[k].y *= sc;
                    acc[k].z *= sc; acc[k].w *= sc;
                }
                m = d;
            }
            const float w = __expf(d - m);
            Z += w;

            // ---- accumulate phase: re-read row (L2-resident) ----
            #pragma unroll
            for (int k = 0; k < 16; ++k) {
                float4 x = cb[rowb + k * 64 + lane];
                acc[k].x = fmaf(w, x.x, acc[k].x);
                acc[k].y = fmaf(w, x.y, acc[k].y);
                acc[k].z = fmaf(w, x.z, acc[k].z);
                acc[k].w = fmaf(w, x.w, acc[k].w);
            }
        }

        float4* __restrict__ pb = (float4*)(partial + (size_t)gw * Q);
        #pragma unroll
        for (int k = 0; k < 16; ++k) pb[k * 64 + lane] = acc[k];
        if (lane == 0) { m_arr[gw] = m; Z_arr[gw] = Z; }
    } else {
        // ---- Family B: out1[i] = Kw[i, 0:Q] . q ----
        const int gw2 = (blockIdx.x - NCBLK) * 4 + wid;  // 0..2047
        for (int rr = 0; rr < RWK; ++rr) {
            const int i = gw2 * RWK + rr;                // 0..4095
            const float4* __restrict__ row = (const float4*)(Kw + (size_t)i * (2 * Q));
            float a = 0.f;
            #pragma unroll 4
            for (int k = 0; k < 16; ++k) {
                float4 x = row[k * 64 + lane];
                float4 y = qv[k * 64 + lane];
                a = fmaf(x.x, y.x, a); a = fmaf(x.y, y.y, a);
                a = fmaf(x.z, y.z, a); a = fmaf(x.w, y.w, a);
            }
            #pragma unroll
            for (int off = 32; off > 0; off >>= 1) a += __shfl_down(a, off, 64);
            if (lane == 0) out1[i] = a;
        }
    }
}

// ---------------------------------------------------------------------------
// K2: merge NCW partials: s_t[j] = (1/Z_tot) * sum_b exp(m_b - M) * p_b[j]
//     64 blocks x 16 f4-cols; 16 b-groups sweep NCW.  (R8-proven structure)
// ---------------------------------------------------------------------------
__global__ __launch_bounds__(256) void merge_kernel(
    const float* __restrict__ partial, const float* __restrict__ m_arr,
    const float* __restrict__ Z_arr, float* __restrict__ s_t)
{
    __shared__ float w_s[NCW];          // 8 KB
    __shared__ float redm[4];
    __shared__ float4 sacc[16][16];     // 4 KB
    const int tid  = threadIdx.x;
    const int lane = tid & 63;
    const int wid  = tid >> 6;

    // M = max_b m_b
    float lm = -3.4e38f;
    for (int b = tid; b < NCW; b += 256) lm = fmaxf(lm, m_arr[b]);
    #pragma unroll
    for (int off = 32; off > 0; off >>= 1) lm = fmaxf(lm, __shfl_down(lm, off, 64));
    if (lane == 0) redm[wid] = lm;
    __syncthreads();
    const float M = fmaxf(fmaxf(redm[0], redm[1]), fmaxf(redm[2], redm[3]));
    __syncthreads();

    // w_b and Z_tot
    float lz = 0.f;
    for (int b = tid; b < NCW; b += 256) {
        const float w = __expf(m_arr[b] - M);
        w_s[b] = w;
        lz = fmaf(w, Z_arr[b], lz);
    }
    #pragma unroll
    for (int off = 32; off > 0; off >>= 1) lz += __shfl_down(lz, off, 64);
    if (lane == 0) redm[wid] = lz;
    __syncthreads();
    const float invZ = 1.f / (redm[0] + redm[1] + redm[2] + redm[3]);

    // weighted column sums
    const int cidx = tid & 15;               // column within block
    const int g    = tid >> 4;               // 0..15 b-group
    const int c4   = blockIdx.x * 16 + cidx; // global float4 column
    const float4* __restrict__ p = (const float4*)partial;
    float4 acc = make_float4(0.f, 0.f, 0.f, 0.f);
    for (int b = g; b < NCW; b += 16) {
        const float w = w_s[b];
        float4 v = p[(size_t)b * (Q / 4) + c4];
        acc.x = fmaf(w, v.x, acc.x); acc.y = fmaf(w, v.y, acc.y);
        acc.z = fmaf(w, v.z, acc.z); acc.w = fmaf(w, v.w, acc.w);
    }
    sacc[g][cidx] = acc;
    __syncthreads();
    if (g == 0) {
        float4 t = sacc[0][cidx];
        #pragma unroll
        for (int gg = 1; gg < 16; ++gg) {
            float4 u = sacc[gg][cidx];
            t.x += u.x; t.y += u.y; t.z += u.z; t.w += u.w;
        }
        t.x *= invZ; t.y *= invZ; t.z *= invZ; t.w *= invZ;
        ((float4*)s_t)[c4] = t;
    }
}

// ---------------------------------------------------------------------------
// K3: out[i] = out1[i] + Kw[i, Q:2Q] . s_t   (one wave per row, R6-proven)
// ---------------------------------------------------------------------------
__global__ __launch_bounds__(256) void out_kernel(
    const float* __restrict__ Kw, const float* __restrict__ s_t,
    const float* __restrict__ out1, float* __restrict__ out)
{
    const int lane = threadIdx.x & 63;
    const int wid  = threadIdx.x >> 6;
    const int i = blockIdx.x * 4 + wid;
    const float4* __restrict__ row = (const float4*)(Kw + (size_t)i * (2 * Q) + Q);
    const float4* __restrict__ sv  = (const float4*)s_t;
    float a = 0.f;
    #pragma unroll 4
    for (int it = 0; it < 16; ++it) {
        const int idx = it * 64 + lane;
        float4 x = row[idx], y = sv[idx];
        a = fmaf(x.x, y.x, a); a = fmaf(x.y, y.y, a);
        a = fmaf(x.z, y.z, a); a = fmaf(x.w, y.w, a);
    }
    #pragma unroll
    for (int off = 32; off > 0; off >>= 1) a += __shfl_down(a, off, 64);
    if (lane == 0) out[i] = out1[i] + a;
}

// ---------------------------------------------------------------------------
extern "C" void kernel_launch(void* const* d_in, const int* in_sizes, int n_in,
                              void* d_out, int out_size, void* d_ws, size_t ws_size,
                              hipStream_t stream)
{
    const float* query = (const float*)d_in[0];   // [Q]
    const float* ctx   = (const float*)d_in[1];   // [L, Q]
    const float* Kw    = (const float*)d_in[2];   // [Q, 2Q]
    float* out = (float*)d_out;                   // [Q]

    // workspace layout (floats)
    float* ws      = (float*)d_ws;
    float* m_arr   = ws;                          // NCW   = 2048
    float* Z_arr   = ws + NCW;                    // NCW   = 2048
    float* out1    = ws + 2 * NCW;                // Q     = 4096
    float* s_t     = ws + 2 * NCW + Q;            // Q     = 4096
    float* partial = ws + 2 * NCW + 2 * Q;        // NCW*Q = 32 MiB

    pass1_kernel<<<NCBLK + NKBLK, 256, 0, stream>>>(query, ctx, Kw,
                                                    partial, m_arr, Z_arr, out1);
    merge_kernel<<<Q / 4 / 16, 256, 0, stream>>>(partial, m_arr, Z_arr, s_t);
    out_kernel<<<Q / 4, 256, 0, stream>>>(Kw, s_t, out1, out);
}

// Round 13
// 90.897 us; speedup vs baseline: 1.2041x; 1.2041x over previous
//
#include <hip/hip_runtime.h>

#define Q 4096
#define L 8192

// ---------------------------------------------------------------------------
// K1: score[l] = ctx[l].q — wave-per-row, q staged in LDS (halves VMEM issue).
//     2048 blocks x 4 waves. One barrier (q stage), then pure HBM stream.
// ---------------------------------------------------------------------------
__global__ __launch_bounds__(256) void score_kernel(
    const float* __restrict__ ctx, const float* __restrict__ qvec,
    float* __restrict__ score)
{
    __shared__ float4 qs[Q / 4];        // 16 KB
    const int tid  = threadIdx.x;
    const int lane = tid & 63;
    const int wid  = tid >> 6;
    const float4* __restrict__ qv = (const float4*)qvec;

    #pragma unroll
    for (int k = 0; k < 4; ++k) qs[tid + k * 256] = qv[tid + k * 256];
    __syncthreads();

    const int w = blockIdx.x * 4 + wid;               // row id 0..8191
    const float4* __restrict__ row = (const float4*)(ctx + (size_t)w * Q);

    float a0 = 0.f, a1 = 0.f, a2 = 0.f, a3 = 0.f;
    #pragma unroll
    for (int c = 0; c < 16; c += 4) {
        float4 x0 = row[(c + 0) * 64 + lane], y0 = qs[(c + 0) * 64 + lane];
        float4 x1 = row[(c + 1) * 64 + lane], y1 = qs[(c + 1) * 64 + lane];
        float4 x2 = row[(c + 2) * 64 + lane], y2 = qs[(c + 2) * 64 + lane];
        float4 x3 = row[(c + 3) * 64 + lane], y3 = qs[(c + 3) * 64 + lane];
        a0 = fmaf(x0.x, y0.x, a0); a0 = fmaf(x0.y, y0.y, a0);
        a0 = fmaf(x0.z, y0.z, a0); a0 = fmaf(x0.w, y0.w, a0);
        a1 = fmaf(x1.x, y1.x, a1); a1 = fmaf(x1.y, y1.y, a1);
        a1 = fmaf(x1.z, y1.z, a1); a1 = fmaf(x1.w, y1.w, a1);
        a2 = fmaf(x2.x, y2.x, a2); a2 = fmaf(x2.y, y2.y, a2);
        a2 = fmaf(x2.z, y2.z, a2); a2 = fmaf(x2.w, y2.w, a2);
        a3 = fmaf(x3.x, y3.x, a3); a3 = fmaf(x3.y, y3.y, a3);
        a3 = fmaf(x3.z, y3.z, a3); a3 = fmaf(x3.w, y3.w, a3);
    }
    float d = (a0 + a1) + (a2 + a3);
    #pragma unroll
    for (int off = 32; off > 0; off >>= 1) d += __shfl_down(d, off, 64);
    if (lane == 0) score[w] = d;
}

// ---------------------------------------------------------------------------
// K2: att = softmax(score), normalized. Single 1024-thread block.
// ---------------------------------------------------------------------------
__global__ __launch_bounds__(1024) void softmax_kernel(
    const float* __restrict__ score, float* __restrict__ att)
{
    __shared__ float redm[16];
    __shared__ float reds[16];
    const int tid  = threadIdx.x;
    const int lane = tid & 63;
    const int wid  = tid >> 6;

    float m = -3.4e38f;
    for (int i = tid; i < L; i += 1024) m = fmaxf(m, score[i]);
    #pragma unroll
    for (int off = 32; off > 0; off >>= 1) m = fmaxf(m, __shfl_down(m, off, 64));
    if (lane == 0) redm[wid] = m;
    __syncthreads();
    float M = redm[0];
    #pragma unroll
    for (int w = 1; w < 16; ++w) M = fmaxf(M, redm[w]);

    float s = 0.f;
    for (int i = tid; i < L; i += 1024) s += __expf(score[i] - M);
    #pragma unroll
    for (int off = 32; off > 0; off >>= 1) s += __shfl_down(s, off, 64);
    if (lane == 0) reds[wid] = s;
    __syncthreads();
    float Z = 0.f;
    #pragma unroll
    for (int w = 0; w < 16; ++w) Z += reds[w];
    const float inv = 1.0f / Z;

    for (int i = tid; i < L; i += 1024) att[i] = __expf(score[i] - M) * inv;
}

// ---------------------------------------------------------------------------
// K3: weighted sum. 1024 blocks = 4 col-chunks x 256 row-chunks (32 rows):
//     4 blocks/CU (vs R1's 0.5!). Thread owns one float4 column; one cheap
//     barrier (att stage). ctx re-read should be L3-resident from K1.
// ---------------------------------------------------------------------------
__global__ __launch_bounds__(256) void wsum_kernel(
    const float* __restrict__ ctx, const float* __restrict__ att,
    float* __restrict__ partial)
{
    __shared__ float att_s[32];
    const int cc  = blockIdx.x & 3;          // col chunk 0..3
    const int rc  = blockIdx.x >> 2;         // row chunk 0..255
    const int tid = threadIdx.x;
    const int col = cc * 256 + tid;          // float4 column

    if (tid < 32) att_s[tid] = att[rc * 32 + tid];
    __syncthreads();

    const float4* __restrict__ cb = (const float4*)ctx;
    const int r0 = rc * 32;
    float4 acc = make_float4(0.f, 0.f, 0.f, 0.f);
    #pragma unroll 8
    for (int r = 0; r < 32; ++r) {
        const float a = att_s[r];
        float4 v = cb[(size_t)(r0 + r) * (Q / 4) + col];
        acc.x = fmaf(a, v.x, acc.x);
        acc.y = fmaf(a, v.y, acc.y);
        acc.z = fmaf(a, v.z, acc.z);
        acc.w = fmaf(a, v.w, acc.w);
    }
    ((float4*)partial)[(size_t)rc * (Q / 4) + col] = acc;
}

// ---------------------------------------------------------------------------
// K4: s_t[j] = sum over 256 partial rows. 16 blocks x 256 threads,
//     4 row-groups of 64 via LDS combine.
// ---------------------------------------------------------------------------
__global__ __launch_bounds__(256) void reduce_kernel(
    const float* __restrict__ partial, float* __restrict__ s_t)
{
    __shared__ float4 sacc[4][64];
    const int c  = threadIdx.x & 63;              // col within block
    const int g  = threadIdx.x >> 6;              // 0..3 row-group
    const int c4 = blockIdx.x * 64 + c;           // global float4 column
    const float4* __restrict__ p = (const float4*)partial;

    float4 acc = make_float4(0.f, 0.f, 0.f, 0.f);
    for (int b = g; b < 256; b += 4) {
        float4 v = p[(size_t)b * (Q / 4) + c4];
        acc.x += v.x; acc.y += v.y; acc.z += v.z; acc.w += v.w;
    }
    sacc[g][c] = acc;
    __syncthreads();
    if (g == 0) {
        float4 t = sacc[0][c], u1 = sacc[1][c], u2 = sacc[2][c], u3 = sacc[3][c];
        t.x += u1.x + u2.x + u3.x;
        t.y += u1.y + u2.y + u3.y;
        t.z += u1.z + u2.z + u3.z;
        t.w += u1.w + u2.w + u3.w;
        ((float4*)s_t)[c4] = t;
    }
}

// ---------------------------------------------------------------------------
// K5: out[i] = Kw[i,:] . gamma, gamma=[q; s_t] staged in 32 KB LDS.
//     Wave-per-row over the full contiguous 32 KB Kw row. One barrier.
// ---------------------------------------------------------------------------
__global__ __launch_bounds__(256) void out_kernel(
    const float* __restrict__ Kw, const float* __restrict__ qvec,
    const float* __restrict__ s_t, float* __restrict__ out)
{
    __shared__ float4 gs[2 * Q / 4];    // 32 KB
    const int tid  = threadIdx.x;
    const int lane = tid & 63;
    const int wid  = tid >> 6;
    const float4* __restrict__ qv = (const float4*)qvec;
    const float4* __restrict__ sv = (const float4*)s_t;

    #pragma unroll
    for (int k = 0; k < 4; ++k) gs[tid + k * 256] = qv[tid + k * 256];
    #pragma unroll
    for (int k = 0; k < 4; ++k) gs[1024 + tid + k * 256] = sv[tid + k * 256];
    __syncthreads();

    const int i = blockIdx.x * 4 + wid;               // 0..4095
    const float4* __restrict__ row = (const float4*)(Kw + (size_t)i * (2 * Q));

    float a0 = 0.f, a1 = 0.f, a2 = 0.f, a3 = 0.f;
    #pragma unroll
    for (int c = 0; c < 32; c += 4) {
        float4 x0 = row[(c + 0) * 64 + lane], y0 = gs[(c + 0) * 64 + lane];
        float4 x1 = row[(c + 1) * 64 + lane], y1 = gs[(c + 1) * 64 + lane];
        float4 x2 = row[(c + 2) * 64 + lane], y2 = gs[(c + 2) * 64 + lane];
        float4 x3 = row[(c + 3) * 64 + lane], y3 = gs[(c + 3) * 64 + lane];
        a0 = fmaf(x0.x, y0.x, a0); a0 = fmaf(x0.y, y0.y, a0);
        a0 = fmaf(x0.z, y0.z, a0); a0 = fmaf(x0.w, y0.w, a0);
        a1 = fmaf(x1.x, y1.x, a1); a1 = fmaf(x1.y, y1.y, a1);
        a1 = fmaf(x1.z, y1.z, a1); a1 = fmaf(x1.w, y1.w, a1);
        a2 = fmaf(x2.x, y2.x, a2); a2 = fmaf(x2.y, y2.y, a2);
        a2 = fmaf(x2.z, y2.z, a2); a2 = fmaf(x2.w, y2.w, a2);
        a3 = fmaf(x3.x, y3.x, a3); a3 = fmaf(x3.y, y3.y, a3);
        a3 = fmaf(x3.z, y3.z, a3); a3 = fmaf(x3.w, y3.w, a3);
    }
    float d = (a0 + a1) + (a2 + a3);
    #pragma unroll
    for (int off = 32; off > 0; off >>= 1) d += __shfl_down(d, off, 64);
    if (lane == 0) out[i] = d;
}

// ---------------------------------------------------------------------------
extern "C" void kernel_launch(void* const* d_in, const int* in_sizes, int n_in,
                              void* d_out, int out_size, void* d_ws, size_t ws_size,
                              hipStream_t stream)
{
    const float* query = (const float*)d_in[0];   // [Q]
    const float* ctx   = (const float*)d_in[1];   // [L, Q]
    const float* Kw    = (const float*)d_in[2];   // [Q, 2Q]
    float* out = (float*)d_out;                   // [Q]

    // workspace layout (floats)
    float* ws      = (float*)d_ws;
    float* score   = ws;                          // 8192
    float* att     = ws + L;                      // 8192
    float* s_t     = ws + 2 * L;                  // 4096
    float* partial = ws + 2 * L + Q;              // 256*4096 = 4 MiB

    score_kernel<<<L / 4, 256, 0, stream>>>(ctx, query, score);
    softmax_kernel<<<1, 1024, 0, stream>>>(score, att);
    wsum_kernel<<<1024, 256, 0, stream>>>(ctx, att, partial);
    reduce_kernel<<<Q / 4 / 64, 256, 0, stream>>>(partial, s_t);
    out_kernel<<<Q / 4, 256, 0, stream>>>(Kw, query, s_t, out);
}

// Round 14
// 70.892 us; speedup vs baseline: 1.5439x; 1.2822x over previous
//
#include <hip/hip_runtime.h>

#define Q 4096
#define L 8192
#define NCB 1024               // ctx blocks in K1
#define RPB (L / NCB)          // 8 rows per ctx block
#define NOB 256                // out1 blocks in K1 (4 waves each, 4 rows/wave)

// ---------------------------------------------------------------------------
// K1a (blocks 0..NCB-1): online softmax-weighted sum over 8 ctx rows.
//   IDENTICAL to the 70.7us round-6 kernel EXCEPT the per-row block barrier:
//   __syncthreads() (which drains vmcnt(0), killing the next-row prefetch)
//   is replaced by   s_waitcnt lgkmcnt(0) + raw s_barrier   so the 4
//   prefetched global_load_dwordx4 stay in flight across the barrier
//   (m201-verified counted-vmcnt pattern). sred is double-buffered, so
//   buffer R&1 is never rewritten until barrier R+1 has passed.
// K1b (blocks NCB..NCB+NOB-1): out1[i] = Kw[i, 0:Q] . q (unchanged).
// ---------------------------------------------------------------------------
__global__ __launch_bounds__(256) void k1_kernel(
    const float* __restrict__ qvec, const float* __restrict__ ctx,
    const float* __restrict__ Kw,
    float* __restrict__ partial, float* __restrict__ m_arr,
    float* __restrict__ Z_arr, float* __restrict__ out1)
{
    __shared__ float4 qs4[Q / 4];      // 16 KB staged query
    __shared__ float sred[2][4];
    const int tid  = threadIdx.x;
    const int lane = tid & 63;
    const int wid  = tid >> 6;

    if (blockIdx.x < NCB) {
        const float4* __restrict__ qg = (const float4*)qvec;
        const float4* __restrict__ cb = (const float4*)ctx;
        const size_t base = (size_t)blockIdx.x * RPB * (Q / 4);

        // stage q into LDS (one standard barrier, once)
        #pragma unroll
        for (int k = 0; k < 4; ++k) qs4[tid + k * 256] = qg[tid + k * 256];
        __syncthreads();

        float4 va[4], vb[4];
        #pragma unroll
        for (int k = 0; k < 4; ++k) va[k] = cb[base + tid + k * 256];

        float4 acc[4];
        #pragma unroll
        for (int k = 0; k < 4; ++k) acc[k] = make_float4(0.f, 0.f, 0.f, 0.f);
        float m = -3.4e38f, Z = 0.f;

        // process(v, r): dot vs LDS q, reduce with NON-DRAINING barrier,
        // online update. Prefetched global loads stay in flight.
        #define PROCESS(V, R)                                                  \
        {                                                                      \
            float d = 0.f;                                                     \
            _Pragma("unroll")                                                  \
            for (int k = 0; k < 4; ++k) {                                      \
                const float4 qk = qs4[tid + k * 256];                          \
                d = fmaf((V)[k].x, qk.x, d); d = fmaf((V)[k].y, qk.y, d);      \
                d = fmaf((V)[k].z, qk.z, d); d = fmaf((V)[k].w, qk.w, d);      \
            }                                                                  \
            _Pragma("unroll")                                                  \
            for (int off = 32; off > 0; off >>= 1)                             \
                d += __shfl_down(d, off, 64);                                  \
            if (lane == 0) sred[(R) & 1][wid] = d;                             \
            asm volatile("s_waitcnt lgkmcnt(0)" ::: "memory");                 \
            __builtin_amdgcn_s_barrier();                                      \
            const float s = sred[(R) & 1][0] + sred[(R) & 1][1] +              \
                            sred[(R) & 1][2] + sred[(R) & 1][3];               \
            if (s > m) {                                                       \
                const float sc = __expf(m - s);                                \
                Z *= sc;                                                       \
                _Pragma("unroll")                                              \
                for (int k = 0; k < 4; ++k) {                                  \
                    acc[k].x *= sc; acc[k].y *= sc;                            \
                    acc[k].z *= sc; acc[k].w *= sc;                            \
                }                                                              \
                m = s;                                                         \
            }                                                                  \
            const float w = __expf(s - m);                                     \
            Z += w;                                                            \
            _Pragma("unroll")                                                  \
            for (int k = 0; k < 4; ++k) {                                      \
                acc[k].x = fmaf(w, (V)[k].x, acc[k].x);                        \
                acc[k].y = fmaf(w, (V)[k].y, acc[k].y);                        \
                acc[k].z = fmaf(w, (V)[k].z, acc[k].z);                        \
                acc[k].w = fmaf(w, (V)[k].w, acc[k].w);                        \
            }                                                                  \
        }

        #pragma unroll
        for (int rp = 0; rp < RPB; rp += 2) {
            // prefetch row rp+1 while processing rp (in va)
            #pragma unroll
            for (int k = 0; k < 4; ++k)
                vb[k] = cb[base + (size_t)(rp + 1) * (Q / 4) + tid + k * 256];
            PROCESS(va, rp)
            // prefetch row rp+2 while processing rp+1 (in vb)
            if (rp + 2 < RPB) {
                #pragma unroll
                for (int k = 0; k < 4; ++k)
                    va[k] = cb[base + (size_t)(rp + 2) * (Q / 4) + tid + k * 256];
            }
            PROCESS(vb, rp + 1)
        }
        #undef PROCESS

        float4* __restrict__ pb = (float4*)(partial + (size_t)blockIdx.x * Q);
        #pragma unroll
        for (int k = 0; k < 4; ++k) pb[tid + k * 256] = acc[k];
        if (tid == 0) { m_arr[blockIdx.x] = m; Z_arr[blockIdx.x] = Z; }
    } else {
        // ---- out1 = Kw[:, 0:Q] . q, one wave per row, 4 rows per wave ----
        const int b = blockIdx.x - NCB;
        const float4* __restrict__ qv = (const float4*)qvec;
        for (int rr = 0; rr < 4; ++rr) {
            const int i = (b * 4 + wid) + rr * 1024;
            const float4* __restrict__ row = (const float4*)(Kw + (size_t)i * (2 * Q));
            float a = 0.f;
            #pragma unroll 4
            for (int it = 0; it < 16; ++it) {
                const int idx = it * 64 + lane;
                float4 x = row[idx], y = qv[idx];
                a = fmaf(x.x, y.x, a); a = fmaf(x.y, y.y, a);
                a = fmaf(x.z, y.z, a); a = fmaf(x.w, y.w, a);
            }
            #pragma unroll
            for (int off = 32; off > 0; off >>= 1) a += __shfl_down(a, off, 64);
            if (lane == 0) out1[i] = a;
        }
    }
}

// ---------------------------------------------------------------------------
// K2: merge the NCB partials:  s_t[j] = (1/Z_tot) * sum_b exp(m_b - M) * p_b[j]
//     64 blocks; each block owns 16 float4 columns; 16 b-groups sweep NCB.
//     (verbatim from the 70.7us config)
// ---------------------------------------------------------------------------
__global__ __launch_bounds__(256) void k2_kernel(
    const float* __restrict__ partial, const float* __restrict__ m_arr,
    const float* __restrict__ Z_arr, float* __restrict__ s_t)
{
    __shared__ float w_s[NCB];          // 4 KB
    __shared__ float redm[4];
    __shared__ float4 sacc[16][16];     // 4 KB
    const int tid  = threadIdx.x;
    const int lane = tid & 63;
    const int wid  = tid >> 6;

    // M = max_b m_b
    float lm = -3.4e38f;
    for (int b = tid; b < NCB; b += 256) lm = fmaxf(lm, m_arr[b]);
    #pragma unroll
    for (int off = 32; off > 0; off >>= 1) lm = fmaxf(lm, __shfl_down(lm, off, 64));
    if (lane == 0) redm[wid] = lm;
    __syncthreads();
    const float M = fmaxf(fmaxf(redm[0], redm[1]), fmaxf(redm[2], redm[3]));
    __syncthreads();

    // w_b and Z_tot
    float lz = 0.f;
    for (int b = tid; b < NCB; b += 256) {
        const float w = __expf(m_arr[b] - M);
        w_s[b] = w;
        lz = fmaf(w, Z_arr[b], lz);
    }
    #pragma unroll
    for (int off = 32; off > 0; off >>= 1) lz += __shfl_down(lz, off, 64);
    if (lane == 0) redm[wid] = lz;
    __syncthreads();
    const float invZ = 1.f / (redm[0] + redm[1] + redm[2] + redm[3]);

    // weighted column sums
    const int cidx = tid & 15;               // column within block
    const int g    = tid >> 4;               // 0..15 b-group
    const int c4   = blockIdx.x * 16 + cidx; // global float4 column
    const float4* __restrict__ p = (const float4*)partial;
    float4 acc = make_float4(0.f, 0.f, 0.f, 0.f);
    for (int b = g; b < NCB; b += 16) {
        const float w = w_s[b];
        float4 v = p[(size_t)b * (Q / 4) + c4];
        acc.x = fmaf(w, v.x, acc.x); acc.y = fmaf(w, v.y, acc.y);
        acc.z = fmaf(w, v.z, acc.z); acc.w = fmaf(w, v.w, acc.w);
    }
    sacc[g][cidx] = acc;
    __syncthreads();
    if (g == 0) {
        float4 t = sacc[0][cidx];
        #pragma unroll
        for (int gg = 1; gg < 16; ++gg) {
            float4 u = sacc[gg][cidx];
            t.x += u.x; t.y += u.y; t.z += u.z; t.w += u.w;
        }
        t.x *= invZ; t.y *= invZ; t.z *= invZ; t.w *= invZ;
        ((float4*)s_t)[c4] = t;
    }
}

// ---------------------------------------------------------------------------
// K3: out[i] = out1[i] + Kw[i, Q:2Q] . s_t    (one wave per row)
//     (verbatim from the 70.7us config)
// ---------------------------------------------------------------------------
__global__ __launch_bounds__(256) void k3_kernel(
    const float* __restrict__ Kw, const float* __restrict__ s_t,
    const float* __restrict__ out1, float* __restrict__ out)
{
    const int lane = threadIdx.x & 63;
    const int wid  = threadIdx.x >> 6;
    const int i = blockIdx.x * 4 + wid;
    const float4* __restrict__ row = (const float4*)(Kw + (size_t)i * (2 * Q) + Q);
    const float4* __restrict__ sv  = (const float4*)s_t;
    float a = 0.f;
    #pragma unroll 4
    for (int it = 0; it < 16; ++it) {
        const int idx = it * 64 + lane;
        float4 x = row[idx], y = sv[idx];
        a = fmaf(x.x, y.x, a); a = fmaf(x.y, y.y, a);
        a = fmaf(x.z, y.z, a); a = fmaf(x.w, y.w, a);
    }
    #pragma unroll
    for (int off = 32; off > 0; off >>= 1) a += __shfl_down(a, off, 64);
    if (lane == 0) out[i] = out1[i] + a;
}

// ---------------------------------------------------------------------------
extern "C" void kernel_launch(void* const* d_in, const int* in_sizes, int n_in,
                              void* d_out, int out_size, void* d_ws, size_t ws_size,
                              hipStream_t stream)
{
    const float* query = (const float*)d_in[0];   // [Q]
    const float* ctx   = (const float*)d_in[1];   // [L, Q]
    const float* Kw    = (const float*)d_in[2];   // [Q, 2Q]
    float* out = (float*)d_out;                   // [Q]

    // workspace layout (floats)
    float* ws      = (float*)d_ws;
    float* m_arr   = ws;                          // NCB   = 1024
    float* Z_arr   = ws + NCB;                    // NCB   = 1024
    float* out1    = ws + 2 * NCB;                // Q     = 4096
    float* s_t     = ws + 2 * NCB + Q;            // Q     = 4096
    float* partial = ws + 2 * NCB + 2 * Q;        // NCB*Q = 16 MiB

    k1_kernel<<<NCB + NOB, 256, 0, stream>>>(query, ctx, Kw,
                                             partial, m_arr, Z_arr, out1);
    k2_kernel<<<Q / 4 / 16, 256, 0, stream>>>(partial, m_arr, Z_arr, s_t);
    k3_kernel<<<Q / 4, 256, 0, stream>>>(Kw, s_t, out1, out);
}